// Round 1
// 771.661 us; speedup vs baseline: 1.0468x; 1.0468x over previous
//
#include <hip/hip_runtime.h>
#include <math.h>

// Problem constants: B=8, N=128, D=512, H=16, DK=32
// Threshold is 2% of absmax(ref) -> bf16 MFMA for the two 131072x512x512 GEMMs.

using f32x4  = __attribute__((ext_vector_type(4))) float;
using bf16x8 = __attribute__((ext_vector_type(8))) short;

typedef const __attribute__((address_space(1))) unsigned int* gas_u32p;
typedef __attribute__((address_space(3))) unsigned int* las_u32p;

// async global->LDS, 16B per lane; LDS dest = wave-uniform base + lane*16
__device__ __forceinline__ void gll16(const void* gsrc, void* ldst) {
  __builtin_amdgcn_global_load_lds((gas_u32p)gsrc, (las_u32p)ldst, 16, 0, 0);
}

__device__ __forceinline__ unsigned short f2bf(float f) {
  union { float f; unsigned u; } v; v.f = f;
  unsigned u = v.u;
  u += 0x7FFFu + ((u >> 16) & 1u);      // round-to-nearest-even
  return (unsigned short)(u >> 16);
}
__device__ __forceinline__ float bf2f(unsigned short h) {
  union { unsigned u; float f; } v; v.u = ((unsigned)h) << 16; return v.f;
}
// pack two f32 -> dword of 2 bf16 (round-half-up via +0x8000, then v_perm)
__device__ __forceinline__ unsigned pack2(float lo, float hi) {
  union { float f; unsigned u; } a, b; a.f = lo; b.f = hi;
  return __builtin_amdgcn_perm(b.u + 0x8000u, a.u + 0x8000u, 0x07060302u);
}
// scale a dword of 2 bf16 by mv, repack
__device__ __forceinline__ unsigned scale_pair(unsigned u, float mv) {
  union { unsigned u; float f; } lo, hi;
  lo.u = u << 16; hi.u = u & 0xFFFF0000u;
  float a = lo.f * mv, b = hi.f * mv;
  return pack2(a, b);
}

// ---------------------------------------------------------------------------
// Transpose-convert a 512x512 f32 weight matrix W[k][n] -> WT[n][k] bf16.
__global__ __launch_bounds__(256) void wt_kernel(const float* __restrict__ W,
                                                 unsigned short* __restrict__ WT) {
  __shared__ unsigned short T[64][72];
  int tile = blockIdx.x;                 // 64 tiles of 64x64
  int ti = tile >> 3, tj = tile & 7;
  int k0 = ti * 64, n0 = tj * 64;
  int t = threadIdx.x;
  int r = t >> 2, cq = (t & 3) * 16;
  const float* src = W + (size_t)(k0 + r) * 512 + n0 + cq;
#pragma unroll
  for (int j = 0; j < 16; ++j) T[r][cq + j] = f2bf(src[j]);
  __syncthreads();
  int c = t >> 2, rq = (t & 3) * 16;
  unsigned short* dst = WT + (size_t)(n0 + c) * 512 + k0 + rq;
#pragma unroll
  for (int j = 0; j < 16; ++j) dst[j] = T[rq + j][c];
}

// ---------------------------------------------------------------------------
// Adjacency softmax: adjsm[b,i,:] = softmax_j( mask[b,j] ? -lam*adj[b,i,j] : -inf )
__global__ __launch_bounds__(256) void adj_kernel(const float* __restrict__ adjm,
                                                  const int* __restrict__ mask,
                                                  const float* __restrict__ lam_p,
                                                  float* __restrict__ adjsm) {
  int row = blockIdx.x * 4 + (threadIdx.x >> 6);   // row < B*N = 1024
  int lane = threadIdx.x & 63;
  int b = row >> 7;
  float lam = lam_p[0];
  const float* src = adjm + (size_t)row * 128;
  int m0 = mask[b * 128 + lane], m1 = mask[b * 128 + 64 + lane];
  float x0 = m0 ? -lam * src[lane] : -INFINITY;
  float x1 = m1 ? -lam * src[64 + lane] : -INFINITY;
  float mx = fmaxf(x0, x1);
#pragma unroll
  for (int o = 32; o; o >>= 1) mx = fmaxf(mx, __shfl_xor(mx, o));
  float e0 = __expf(x0 - mx), e1 = __expf(x1 - mx);
  float s = e0 + e1;
#pragma unroll
  for (int o = 32; o; o >>= 1) s += __shfl_xor(s, o);
  float inv = 1.0f / s;
  adjsm[(size_t)row * 128 + lane] = e0 * inv;
  adjsm[(size_t)row * 128 + 64 + lane] = e1 * inv;
}

// ---------------------------------------------------------------------------
// Small GEMM (v1 structure): C[M x 512] = A[M x 512] @ W + bias, f32 in/out.
// grid.x = (M/128)*4.
__global__ __launch_bounds__(256) void gemm_kernel(const float* __restrict__ A,
                                                   const unsigned short* __restrict__ WT,
                                                   const float* __restrict__ bias,
                                                   float* __restrict__ C) {
  __shared__ unsigned short As[128 * 40];
  __shared__ unsigned short Bs[128 * 40];
  const int bid = blockIdx.x;
  const int rb = bid >> 2, cb = bid & 3;
  const int t = threadIdx.x;
  const int row0 = rb * 128, col0 = cb * 128;
  const int wave = t >> 6, lane = t & 63;
  const int wm = wave >> 1, wn = wave & 1;
  const int l15 = lane & 15, q4 = lane >> 4;
  const int arow = t >> 1, ahalf = t & 1;

  f32x4 acc[4][4];
#pragma unroll
  for (int i = 0; i < 4; ++i)
#pragma unroll
    for (int j = 0; j < 4; ++j)
#pragma unroll
      for (int r = 0; r < 4; ++r) acc[i][j][r] = 0.0f;

  for (int ki = 0; ki < 16; ++ki) {
    const int k0 = ki * 32;
    {
      const float* src = A + (size_t)(row0 + arow) * 512 + k0 + ahalf * 16;
      f32x4 v0 = *(const f32x4*)(src + 0);
      f32x4 v1 = *(const f32x4*)(src + 4);
      f32x4 v2 = *(const f32x4*)(src + 8);
      f32x4 v3 = *(const f32x4*)(src + 12);
      union { unsigned short u[16]; uint4 q[2]; } w;
#pragma unroll
      for (int j = 0; j < 4; ++j) {
        w.u[j] = f2bf(v0[j]); w.u[4 + j] = f2bf(v1[j]);
        w.u[8 + j] = f2bf(v2[j]); w.u[12 + j] = f2bf(v3[j]);
      }
      unsigned short* d = &As[arow * 40 + ahalf * 16];
      *(uint4*)d = w.q[0];
      *(uint4*)(d + 8) = w.q[1];
    }
    {
      const unsigned short* src = WT + (size_t)(col0 + arow) * 512 + k0 + ahalf * 16;
      uint4 p0 = *(const uint4*)src;
      uint4 p1 = *(const uint4*)(src + 8);
      unsigned short* d = &Bs[arow * 40 + ahalf * 16];
      *(uint4*)d = p0;
      *(uint4*)(d + 8) = p1;
    }
    __syncthreads();
    bf16x8 af[4], bfr[4];
#pragma unroll
    for (int mt = 0; mt < 4; ++mt)
      af[mt] = *(const bf16x8*)&As[(wm * 64 + mt * 16 + l15) * 40 + q4 * 8];
#pragma unroll
    for (int nt = 0; nt < 4; ++nt)
      bfr[nt] = *(const bf16x8*)&Bs[(wn * 64 + nt * 16 + l15) * 40 + q4 * 8];
#pragma unroll
    for (int mt = 0; mt < 4; ++mt)
#pragma unroll
      for (int nt = 0; nt < 4; ++nt)
        acc[mt][nt] = __builtin_amdgcn_mfma_f32_16x16x32_bf16(af[mt], bfr[nt], acc[mt][nt], 0, 0, 0);
    __syncthreads();
  }
#pragma unroll
  for (int mt = 0; mt < 4; ++mt) {
#pragma unroll
    for (int nt = 0; nt < 4; ++nt) {
      int gcol = col0 + wn * 64 + nt * 16 + l15;
      float bv = bias[gcol];
#pragma unroll
      for (int r = 0; r < 4; ++r) {
        int grow = row0 + wm * 64 + mt * 16 + q4 * 4 + r;
        C[(size_t)grow * 512 + gcol] = acc[mt][nt][r] + bv;
      }
    }
  }
}

// ---------------------------------------------------------------------------
// Big GEMM v3: 128x256 tile, pipelined global_load_lds staging with counted
// vmcnt (T3/T4-lite), XOR-swizzled LDS, fragment-time conversion.
// AMODE 1: A f32 -> C bf16 (K projection). 2-stage pipeline (1-deep prefetch).
// AMODE 2: A bf16, scaled per (row, ki) by msg -> C f32 (edge output).
//          3-stage pipeline (2-deep prefetch, vmcnt(6) counted waits);
//          msg rows for the whole block preloaded once into Ms[16][128].
// grid.x = (M/128)*2; bid>>1 = row block, bid&1 = col block.
// Dynamic LDS: AMODE1 = 2*32768 = 65536 B; AMODE2 = 3*24576 + 8192 = 81920 B.
template <int AMODE>
__global__ __launch_bounds__(256, 2) void gemm2_kernel(
    const void* __restrict__ Aptr, const unsigned short* __restrict__ WT,
    const float* __restrict__ bias, void* __restrict__ Cptr,
    const float* __restrict__ msg) {
  constexpr int DEPTH  = (AMODE == 2) ? 3 : 2;   // LDS stage buffers
  constexpr int ABYTES = (AMODE == 2) ? 8192 : 16384;
  constexpr int STAGEB = ABYTES + 16384;         // A-tile + B-tile per stage
  extern __shared__ char smem[];
  float* Msh = (float*)(smem + DEPTH * STAGEB);  // AMODE2: Ms[16][128]

  const int bid = blockIdx.x;
  const int rb = bid >> 1, cb = bid & 1;
  const int row0 = rb * 128, col0 = cb * 256;
  const int t = threadIdx.x;
  const int wave = t >> 6, lane = t & 63;
  const int wm = wave >> 1, wn = wave & 1;
  const int l15 = lane & 15, q4 = lane >> 4;

  f32x4 acc[4][8];
#pragma unroll
  for (int i = 0; i < 4; ++i)
#pragma unroll
    for (int j = 0; j < 8; ++j)
#pragma unroll
      for (int r = 0; r < 4; ++r) acc[i][j][r] = 0.0f;

  // Stage tile ki into LDS stage s. Per-wave gll16 count: AMODE1=8, AMODE2=6.
  auto STAGE = [&](int ki, int s) {
    const int k0 = ki * 32;
    char* sa = smem + s * STAGEB;
    if (AMODE != 2) {
      const float* A = (const float*)Aptr;
      float* Asf = (float*)sa;                   // 128x32 f32, XOR-swizzled
#pragma unroll
      for (int c = 0; c < 4; ++c) {
        int ar = (wave * 4 + c) * 8 + (lane >> 3);
        int p = (lane & 7) >> 1, h = lane & 1;
        int gcol = ((p ^ (ar & 3)) << 3) + (h << 2);
        gll16(A + (size_t)(row0 + ar) * 512 + k0 + gcol,
              Asf + (size_t)(wave * 4 + c) * 256);
      }
    } else {
      const unsigned short* A = (const unsigned short*)Aptr;
      unsigned short* Abf = (unsigned short*)sa; // 128x32 bf16, XOR-swizzled
#pragma unroll
      for (int c = 0; c < 2; ++c) {
        int ar = (wave * 2 + c) * 16 + (lane >> 2);
        int gq = (lane & 3) ^ (ar & 3);
        gll16(A + (size_t)(row0 + ar) * 512 + k0 + gq * 8,
              Abf + (size_t)(wave * 2 + c) * 512);
      }
    }
    unsigned short* Bsb = (unsigned short*)(sa + ABYTES);  // 256x32 bf16
#pragma unroll
    for (int c = 0; c < 4; ++c) {
      int br = (wave * 4 + c) * 16 + (lane >> 2);
      int gq = (lane & 3) ^ (br & 3);
      gll16(WT + (size_t)(col0 + br) * 512 + k0 + gq * 8,
            Bsb + (size_t)(wave * 4 + c) * 512);
    }
  };

  if (AMODE == 2) {
    // Preload Ms[h][n] = msg[b, h, m, n] for the whole block (8 KB), once.
    // (BK=32 == DK, so K-step ki corresponds exactly to head h=ki.)
    int b = row0 >> 14, m = (row0 >> 7) & 127;
    size_t msbase = (size_t)(b * 16) * 16384 + (size_t)m * 128;
    int h = t >> 4, n8 = (t & 15) * 8;
    const float* mp = msg + msbase + (size_t)h * 16384 + n8;
    f32x4 m0 = *(const f32x4*)mp;
    f32x4 m1 = *(const f32x4*)(mp + 4);
    *(f32x4*)&Msh[h * 128 + n8] = m0;
    *(f32x4*)&Msh[h * 128 + n8 + 4] = m1;
    __syncthreads();   // Ms visible to all waves; drains prologue vmcnt too
  }

  STAGE(0, 0);
  if (DEPTH == 3) STAGE(1, 1);

#pragma unroll
  for (int ki = 0; ki < 16; ++ki) {
    // Wait for tile ki only; keep later tiles' loads in flight (T4).
    if (DEPTH == 3) {
      if (ki < 15) asm volatile("s_waitcnt vmcnt(6)" ::: "memory");
      else         asm volatile("s_waitcnt vmcnt(0)" ::: "memory");
    } else {
      asm volatile("s_waitcnt vmcnt(0)" ::: "memory");
    }
    __builtin_amdgcn_s_barrier();
    __builtin_amdgcn_sched_barrier(0);
    // Issue-early prefetch of tile ki+DEPTH-1 (safe: all waves are past the
    // reads of the buffer it overwrites, enforced by the barrier above).
    if (ki + DEPTH - 1 < 16) STAGE(ki + DEPTH - 1, (ki + DEPTH - 1) % DEPTH);

    char* sc = smem + (ki % DEPTH) * STAGEB;
    unsigned short* Bs = (unsigned short*)(sc + ABYTES);
    bf16x8 bfr[8], af[4];
#pragma unroll
    for (int nt = 0; nt < 8; ++nt) {
      int brow = wn * 128 + nt * 16 + l15;
      bfr[nt] = *(const bf16x8*)&Bs[brow * 32 + ((q4 ^ (brow & 3)) << 3)];
    }
    if (AMODE != 2) {
      float* Asf = (float*)sc;
#pragma unroll
      for (int mt = 0; mt < 4; ++mt) {
        int arow = wm * 64 + mt * 16 + l15;
        const float* ap = &Asf[arow * 32 + ((q4 ^ (arow & 3)) << 3)];
        f32x4 v0 = *(const f32x4*)ap;
        f32x4 v1 = *(const f32x4*)(ap + 4);
        union { unsigned d[4]; bf16x8 v; } u;
        u.d[0] = pack2(v0[0], v0[1]); u.d[1] = pack2(v0[2], v0[3]);
        u.d[2] = pack2(v1[0], v1[1]); u.d[3] = pack2(v1[2], v1[3]);
        af[mt] = u.v;
      }
    } else {
      unsigned short* Abf = (unsigned short*)sc;
#pragma unroll
      for (int mt = 0; mt < 4; ++mt) {
        int arow = wm * 64 + mt * 16 + l15;
        union { unsigned d[4]; bf16x8 v; } u;
        u.v = *(const bf16x8*)&Abf[arow * 32 + ((q4 ^ (arow & 3)) << 3)];
        float mv = Msh[ki * 128 + arow];
        u.d[0] = scale_pair(u.d[0], mv);
        u.d[1] = scale_pair(u.d[1], mv);
        u.d[2] = scale_pair(u.d[2], mv);
        u.d[3] = scale_pair(u.d[3], mv);
        af[mt] = u.v;
      }
    }
#pragma unroll
    for (int mt = 0; mt < 4; ++mt)
#pragma unroll
      for (int nt = 0; nt < 8; ++nt)
        acc[mt][nt] = __builtin_amdgcn_mfma_f32_16x16x32_bf16(af[mt], bfr[nt], acc[mt][nt], 0, 0, 0);
  }
  // ---- epilogue
#pragma unroll
  for (int mt = 0; mt < 4; ++mt) {
#pragma unroll
    for (int nt = 0; nt < 8; ++nt) {
      int gcol = col0 + wn * 128 + nt * 16 + l15;
      float bv = bias[gcol];
#pragma unroll
      for (int r = 0; r < 4; ++r) {
        int grow = row0 + wm * 64 + mt * 16 + q4 * 4 + r;
        float val = acc[mt][nt][r] + bv;
        if (AMODE == 1)
          ((unsigned short*)Cptr)[(size_t)grow * 512 + gcol] = f2bf(val);
        else
          ((float*)Cptr)[(size_t)grow * 512 + gcol] = val;
      }
    }
  }
}

// ---------------------------------------------------------------------------
// Scores: one block per (b,m). Computes for every n,h:
//   sout[b,h,m,n] = scale * q[b,m,h*32:]·K[b,m,n,h*32:]   (masked on n)
//   sinT[b,h,m,n] = scale * q[b,n,h*32:]·K[b,m,n,h*32:]   (= in_scores[b,h,n,m], masked on m)
__global__ __launch_bounds__(512) void scores_kernel(const unsigned short* __restrict__ Kbf,
                                                     const float* __restrict__ qw,
                                                     const int* __restrict__ mask,
                                                     float* __restrict__ sout,
                                                     float* __restrict__ sinT) {
  __shared__ float lso[16 * 9];
  __shared__ float lsi[16 * 9];
  const int bm = blockIdx.x;             // b*128 + m
  const int b = bm >> 7;
  const int t = threadIdx.x;
  const int wave = t >> 6, lane = t & 63;
  const float scale = 0.17677669529663687f;   // 1/sqrt(32)
  const int maskm = mask[bm];
  float qmr[8];
  {
    const float* qp = qw + (size_t)bm * 512 + lane * 8;
    f32x4 a = *(const f32x4*)qp, bq = *(const f32x4*)(qp + 4);
#pragma unroll
    for (int j = 0; j < 4; ++j) { qmr[j] = a[j]; qmr[4 + j] = bq[j]; }
  }
  for (int it = 0; it < 16; ++it) {
    int n = it * 8 + wave;
    const unsigned short* kp = Kbf + ((size_t)bm * 128 + n) * 512 + lane * 8;
    uint4 kv = *(const uint4*)kp;
    const float* qnp = qw + ((size_t)(b * 128 + n)) * 512 + lane * 8;
    f32x4 qa = *(const f32x4*)qnp, qb = *(const f32x4*)(qnp + 4);
    float qnr[8];
#pragma unroll
    for (int j = 0; j < 4; ++j) { qnr[j] = qa[j]; qnr[4 + j] = qb[j]; }
    unsigned vals[4] = {kv.x, kv.y, kv.z, kv.w};
    float so = 0.f, si = 0.f;
#pragma unroll
    for (int j = 0; j < 4; ++j) {
      float k0 = bf2f((unsigned short)(vals[j] & 0xFFFFu));
      float k1 = bf2f((unsigned short)(vals[j] >> 16));
      so += qmr[2 * j] * k0 + qmr[2 * j + 1] * k1;
      si += qnr[2 * j] * k0 + qnr[2 * j + 1] * k1;
    }
    so += __shfl_xor(so, 1); so += __shfl_xor(so, 2);
    si += __shfl_xor(si, 1); si += __shfl_xor(si, 2);
    int maskn = mask[b * 128 + n];
    if ((lane & 3) == 0) {
      int h = lane >> 2;
      lso[h * 9 + wave] = maskn ? so * scale : -INFINITY;
      lsi[h * 9 + wave] = maskm ? si * scale : -INFINITY;
    }
    __syncthreads();
    if (t < 256) {
      int sel = t >> 7, u = t & 127, h = u >> 3, w = u & 7;
      float v = sel ? lsi[h * 9 + w] : lso[h * 9 + w];
      float* dst = sel ? sinT : sout;
      dst[((size_t)(b * 16 + h) * 128 + (bm & 127)) * 128 + it * 8 + w] = v;
    }
    __syncthreads();
  }
}

// ---------------------------------------------------------------------------
// Batched 128x128 transpose: dst[mat][y][x] = src[mat][x][y].
__global__ __launch_bounds__(256) void tr128_kernel(const float* __restrict__ src,
                                                    float* __restrict__ dst) {
  __shared__ float T[64][65];
  int bid = blockIdx.x;
  int mat = bid >> 2, tile = bid & 3;
  int ti = tile >> 1, tj = tile & 1;
  const float* s = src + (size_t)mat * 16384;
  float* d = dst + (size_t)mat * 16384;
  int t = threadIdx.x;
  int r = t >> 2, cq = (t & 3) * 16;
#pragma unroll
  for (int j = 0; j < 16; ++j) T[r][cq + j] = s[(size_t)(ti * 64 + r) * 128 + tj * 64 + cq + j];
  __syncthreads();
  int c = t >> 2, rq = (t & 3) * 16;
#pragma unroll
  for (int j = 0; j < 16; ++j) d[(size_t)(tj * 64 + c) * 128 + ti * 64 + rq + j] = T[rq + j][c];
}

// ---------------------------------------------------------------------------
// In-place row softmax over rows of length 128 (rows = B*H*N).
__global__ __launch_bounds__(256) void rsm_kernel(float* __restrict__ x) {
  int row = blockIdx.x * 4 + (threadIdx.x >> 6);
  int lane = threadIdx.x & 63;
  float* p = x + (size_t)row * 128;
  float a0 = p[lane], a1 = p[lane + 64];
  float mx = fmaxf(a0, a1);
#pragma unroll
  for (int o = 32; o; o >>= 1) mx = fmaxf(mx, __shfl_xor(mx, o));
  float e0 = __expf(a0 - mx), e1 = __expf(a1 - mx);
  float s = e0 + e1;
#pragma unroll
  for (int o = 32; o; o >>= 1) s += __shfl_xor(s, o);
  float inv = 1.0f / s;
  p[lane] = e0 * inv;
  p[lane + 64] = e1 * inv;
}

// ---------------------------------------------------------------------------
// message = (out_attn + in_attn, diag -> in_attn) * adjsm ; in place over in_attn.
__global__ __launch_bounds__(256) void msg_kernel(const float* __restrict__ outat,
                                                  float* __restrict__ inat_msg,
                                                  const float* __restrict__ adjsm) {
  size_t idx = (size_t)blockIdx.x * 256 + threadIdx.x;   // < B*H*N*N
  int c = (int)(idx & 127), r = (int)((idx >> 7) & 127);
  int bh = (int)(idx >> 14), b = bh >> 4;
  float o = outat[idx], in = inat_msg[idx];
  float mv = (r == c) ? in : (o + in);
  mv *= adjsm[((size_t)b * 128 + r) * 128 + c];
  inat_msg[idx] = mv;
}

// ---------------------------------------------------------------------------
// node_hidden: xpre[b, i, h*32+d] = sum_j msg[b,h,i,j] * v[b,j,h*32+d]
__global__ __launch_bounds__(256) void node_kernel(const float* __restrict__ msg,
                                                   const float* __restrict__ vw,
                                                   float* __restrict__ xpre) {
  __shared__ float V[128 * 36];
  __shared__ float Mg[64 * 132];
  int bid = blockIdx.x;
  int bh = bid >> 1, half = bid & 1;
  int b = bh >> 4, h = bh & 15;
  int t = threadIdx.x;
#pragma unroll
  for (int i = 0; i < 16; ++i) {
    int idx = t + i * 256;
    int j = idx >> 5, dk = idx & 31;
    V[j * 36 + dk] = vw[((size_t)b * 128 + j) * 512 + h * 32 + dk];
  }
  const float* mrow = msg + (size_t)bh * 16384 + (size_t)half * 64 * 128;
#pragma unroll
  for (int i = 0; i < 32; ++i) {
    int idx = t + i * 256;
    int r = idx >> 7, c = idx & 127;
    Mg[r * 132 + c] = mrow[idx];
  }
  __syncthreads();
  int il = t >> 2, d0 = (t & 3) * 8;
  float acc[8] = {0, 0, 0, 0, 0, 0, 0, 0};
  for (int j = 0; j < 128; ++j) {
    float mv = Mg[il * 132 + j];
#pragma unroll
    for (int d = 0; d < 8; ++d) acc[d] += mv * V[j * 36 + d0 + d];
  }
  float* xp = xpre + ((size_t)b * 128 + half * 64 + il) * 512 + h * 32 + d0;
#pragma unroll
  for (int d = 0; d < 8; ++d) xp[d] = acc[d];
}

// ---------------------------------------------------------------------------
extern "C" void kernel_launch(void* const* d_in, const int* in_sizes, int n_in,
                              void* d_out, int out_size, void* d_ws, size_t ws_size,
                              hipStream_t stream) {
  const float* q_node   = (const float*)d_in[0];
  const float* v_node   = (const float*)d_in[1];
  const float* key_edge = (const float*)d_in[2];
  const float* adjm     = (const float*)d_in[3];
  const int*   mask     = (const int*)d_in[4];
  const float* Wq = (const float*)d_in[5];
  const float* bq = (const float*)d_in[6];
  const float* Wk = (const float*)d_in[7];
  const float* bk = (const float*)d_in[8];
  const float* Wv = (const float*)d_in[9];
  const float* bv = (const float*)d_in[10];
  const float* Wo = (const float*)d_in[11];
  const float* bo = (const float*)d_in[12];
  const float* We = (const float*)d_in[13];
  const float* be = (const float*)d_in[14];
  const float* lam = (const float*)d_in[15];

  char* ws = (char*)d_ws;
  unsigned short* Kbf   = (unsigned short*)(ws);                 // 134,217,728 B
  float* sout  = (float*)(ws + 134217728);                       //   8,388,608 B
  float* sinT  = (float*)(ws + 142606336);                       //   8,388,608 B
  float* msgb  = (float*)(ws + 150994944);                       //   8,388,608 B
  float* adjsm = (float*)(ws + 159383552);                       //     524,288 B
  float* qw    = (float*)(ws + 159907840);                       //   2,097,152 B
  float* vw    = (float*)(ws + 162004992);                       //   2,097,152 B
  float* xpre  = (float*)(ws + 164102144);                       //   2,097,152 B
  unsigned short* WqT = (unsigned short*)(ws + 166199296);       //   524,288 B each
  unsigned short* WkT = WqT + 262144;
  unsigned short* WvT = WkT + 262144;
  unsigned short* WoT = WvT + 262144;
  unsigned short* WeT = WoT + 262144;
  // total ws usage: 168,820,736 bytes (unchanged)

  float* out_x = (float*)d_out;          // (B,N,D)   = 524288 f32
  float* out_e = out_x + 524288;         // (B,N,N,D) = 67108864 f32

  wt_kernel<<<64, 256, 0, stream>>>(Wq, WqT);
  wt_kernel<<<64, 256, 0, stream>>>(Wk, WkT);
  wt_kernel<<<64, 256, 0, stream>>>(Wv, WvT);
  wt_kernel<<<64, 256, 0, stream>>>(Wo, WoT);
  wt_kernel<<<64, 256, 0, stream>>>(We, WeT);
  adj_kernel<<<256, 256, 0, stream>>>(adjm, mask, lam, adjsm);

  gemm_kernel<<<32, 256, 0, stream>>>(q_node, WqT, bq, qw);
  gemm_kernel<<<32, 256, 0, stream>>>(v_node, WvT, bv, vw);
  gemm2_kernel<1><<<2048, 256, 65536, stream>>>(key_edge, WkT, bk, Kbf, nullptr);

  scores_kernel<<<1024, 512, 0, stream>>>(Kbf, qw, mask, sout, sinT);
  tr128_kernel<<<512, 256, 0, stream>>>(sinT, msgb);
  rsm_kernel<<<4096, 256, 0, stream>>>(sout);
  rsm_kernel<<<4096, 256, 0, stream>>>(msgb);
  msg_kernel<<<8192, 256, 0, stream>>>(sout, msgb, adjsm);
  node_kernel<<<256, 256, 0, stream>>>(msgb, vw, xpre);

  gemm_kernel<<<32, 256, 0, stream>>>(xpre, WoT, bo, out_x);
  gemm2_kernel<2><<<2048, 256, 81920, stream>>>(Kbf, WeT, be, out_e, msgb);
}

// Round 2
// 700.566 us; speedup vs baseline: 1.1530x; 1.1015x over previous
//
#include <hip/hip_runtime.h>
#include <math.h>

// Problem constants: B=8, N=128, D=512, H=16, DK=32
// Threshold is 2% of absmax(ref) -> bf16 MFMA for the two 131072x512x512 GEMMs.

using f32x4  = __attribute__((ext_vector_type(4))) float;
using bf16x8 = __attribute__((ext_vector_type(8))) short;

typedef const __attribute__((address_space(1))) unsigned int* gas_u32p;
typedef __attribute__((address_space(3))) unsigned int* las_u32p;

// async global->LDS, 16B per lane; LDS dest = wave-uniform base + lane*16
__device__ __forceinline__ void gll16(const void* gsrc, void* ldst) {
  __builtin_amdgcn_global_load_lds((gas_u32p)gsrc, (las_u32p)ldst, 16, 0, 0);
}

__device__ __forceinline__ unsigned short f2bf(float f) {
  union { float f; unsigned u; } v; v.f = f;
  unsigned u = v.u;
  u += 0x7FFFu + ((u >> 16) & 1u);      // round-to-nearest-even
  return (unsigned short)(u >> 16);
}
__device__ __forceinline__ float bf2f(unsigned short h) {
  union { unsigned u; float f; } v; v.u = ((unsigned)h) << 16; return v.f;
}
// pack two f32 -> dword of 2 bf16 (round-half-up via +0x8000, then v_perm)
__device__ __forceinline__ unsigned pack2(float lo, float hi) {
  union { float f; unsigned u; } a, b; a.f = lo; b.f = hi;
  return __builtin_amdgcn_perm(b.u + 0x8000u, a.u + 0x8000u, 0x07060302u);
}
// scale a dword of 2 bf16 by mv, repack
__device__ __forceinline__ unsigned scale_pair(unsigned u, float mv) {
  union { unsigned u; float f; } lo, hi;
  lo.u = u << 16; hi.u = u & 0xFFFF0000u;
  float a = lo.f * mv, b = hi.f * mv;
  return pack2(a, b);
}

// ---------------------------------------------------------------------------
// Transpose-convert five 512x512 f32 weight matrices W[k][n] -> WT[n][k] bf16.
// grid = 5*64; bid>>6 selects the matrix, bid&63 the 64x64 tile.
__global__ __launch_bounds__(256) void wt5_kernel(
    const float* __restrict__ W0, const float* __restrict__ W1,
    const float* __restrict__ W2, const float* __restrict__ W3,
    const float* __restrict__ W4,
    unsigned short* __restrict__ T0, unsigned short* __restrict__ T1,
    unsigned short* __restrict__ T2, unsigned short* __restrict__ T3,
    unsigned short* __restrict__ T4) {
  __shared__ unsigned short T[64][72];
  int mat = blockIdx.x >> 6;
  const float* W = (mat == 0) ? W0 : (mat == 1) ? W1 : (mat == 2) ? W2 : (mat == 3) ? W3 : W4;
  unsigned short* WT = (mat == 0) ? T0 : (mat == 1) ? T1 : (mat == 2) ? T2 : (mat == 3) ? T3 : T4;
  int tile = blockIdx.x & 63;            // 64 tiles of 64x64
  int ti = tile >> 3, tj = tile & 7;
  int k0 = ti * 64, n0 = tj * 64;
  int t = threadIdx.x;
  int r = t >> 2, cq = (t & 3) * 16;
  const float* src = W + (size_t)(k0 + r) * 512 + n0 + cq;
#pragma unroll
  for (int j = 0; j < 16; ++j) T[r][cq + j] = f2bf(src[j]);
  __syncthreads();
  int c = t >> 2, rq = (t & 3) * 16;
  unsigned short* dst = WT + (size_t)(n0 + c) * 512 + k0 + rq;
#pragma unroll
  for (int j = 0; j < 16; ++j) dst[j] = T[rq + j][c];
}

// ---------------------------------------------------------------------------
// Adjacency softmax: adjsm[b,i,:] = softmax_j( mask[b,j] ? -lam*adj[b,i,j] : -inf )
__global__ __launch_bounds__(256) void adj_kernel(const float* __restrict__ adjm,
                                                  const int* __restrict__ mask,
                                                  const float* __restrict__ lam_p,
                                                  float* __restrict__ adjsm) {
  int row = blockIdx.x * 4 + (threadIdx.x >> 6);   // row < B*N = 1024
  int lane = threadIdx.x & 63;
  int b = row >> 7;
  float lam = lam_p[0];
  const float* src = adjm + (size_t)row * 128;
  int m0 = mask[b * 128 + lane], m1 = mask[b * 128 + 64 + lane];
  float x0 = m0 ? -lam * src[lane] : -INFINITY;
  float x1 = m1 ? -lam * src[64 + lane] : -INFINITY;
  float mx = fmaxf(x0, x1);
#pragma unroll
  for (int o = 32; o; o >>= 1) mx = fmaxf(mx, __shfl_xor(mx, o));
  float e0 = __expf(x0 - mx), e1 = __expf(x1 - mx);
  float s = e0 + e1;
#pragma unroll
  for (int o = 32; o; o >>= 1) s += __shfl_xor(s, o);
  float inv = 1.0f / s;
  adjsm[(size_t)row * 128 + lane] = e0 * inv;
  adjsm[(size_t)row * 128 + 64 + lane] = e1 * inv;
}

// ---------------------------------------------------------------------------
// Small GEMM body: C[128x128 tile] of A[M x 512] @ W + bias, f32 in/out.
__device__ __forceinline__ void gemm_body(const float* __restrict__ A,
                                          const unsigned short* __restrict__ WT,
                                          const float* __restrict__ bias,
                                          float* __restrict__ C, int rb, int cb) {
  __shared__ unsigned short As[128 * 40];
  __shared__ unsigned short Bs[128 * 40];
  const int t = threadIdx.x;
  const int row0 = rb * 128, col0 = cb * 128;
  const int wave = t >> 6, lane = t & 63;
  const int wm = wave >> 1, wn = wave & 1;
  const int l15 = lane & 15, q4 = lane >> 4;
  const int arow = t >> 1, ahalf = t & 1;

  f32x4 acc[4][4];
#pragma unroll
  for (int i = 0; i < 4; ++i)
#pragma unroll
    for (int j = 0; j < 4; ++j)
#pragma unroll
      for (int r = 0; r < 4; ++r) acc[i][j][r] = 0.0f;

  for (int ki = 0; ki < 16; ++ki) {
    const int k0 = ki * 32;
    {
      const float* src = A + (size_t)(row0 + arow) * 512 + k0 + ahalf * 16;
      f32x4 v0 = *(const f32x4*)(src + 0);
      f32x4 v1 = *(const f32x4*)(src + 4);
      f32x4 v2 = *(const f32x4*)(src + 8);
      f32x4 v3 = *(const f32x4*)(src + 12);
      union { unsigned short u[16]; uint4 q[2]; } w;
#pragma unroll
      for (int j = 0; j < 4; ++j) {
        w.u[j] = f2bf(v0[j]); w.u[4 + j] = f2bf(v1[j]);
        w.u[8 + j] = f2bf(v2[j]); w.u[12 + j] = f2bf(v3[j]);
      }
      unsigned short* d = &As[arow * 40 + ahalf * 16];
      *(uint4*)d = w.q[0];
      *(uint4*)(d + 8) = w.q[1];
    }
    {
      const unsigned short* src = WT + (size_t)(col0 + arow) * 512 + k0 + ahalf * 16;
      uint4 p0 = *(const uint4*)src;
      uint4 p1 = *(const uint4*)(src + 8);
      unsigned short* d = &Bs[arow * 40 + ahalf * 16];
      *(uint4*)d = p0;
      *(uint4*)(d + 8) = p1;
    }
    __syncthreads();
    bf16x8 af[4], bfr[4];
#pragma unroll
    for (int mt = 0; mt < 4; ++mt)
      af[mt] = *(const bf16x8*)&As[(wm * 64 + mt * 16 + l15) * 40 + q4 * 8];
#pragma unroll
    for (int nt = 0; nt < 4; ++nt)
      bfr[nt] = *(const bf16x8*)&Bs[(wn * 64 + nt * 16 + l15) * 40 + q4 * 8];
#pragma unroll
    for (int mt = 0; mt < 4; ++mt)
#pragma unroll
      for (int nt = 0; nt < 4; ++nt)
        acc[mt][nt] = __builtin_amdgcn_mfma_f32_16x16x32_bf16(af[mt], bfr[nt], acc[mt][nt], 0, 0, 0);
    __syncthreads();
  }
#pragma unroll
  for (int mt = 0; mt < 4; ++mt) {
#pragma unroll
    for (int nt = 0; nt < 4; ++nt) {
      int gcol = col0 + wn * 64 + nt * 16 + l15;
      float bv = bias[gcol];
#pragma unroll
      for (int r = 0; r < 4; ++r) {
        int grow = row0 + wm * 64 + mt * 16 + q4 * 4 + r;
        C[(size_t)grow * 512 + gcol] = acc[mt][nt][r] + bv;
      }
    }
  }
}

__global__ __launch_bounds__(256) void gemm_kernel(const float* __restrict__ A,
                                                   const unsigned short* __restrict__ WT,
                                                   const float* __restrict__ bias,
                                                   float* __restrict__ C) {
  gemm_body(A, WT, bias, C, blockIdx.x >> 2, blockIdx.x & 3);
}

// q and v projections in one launch: grid 64, first 32 blocks = q, rest = v.
__global__ __launch_bounds__(256) void gemm_qv_kernel(
    const float* __restrict__ A0, const unsigned short* __restrict__ W0,
    const float* __restrict__ b0, float* __restrict__ C0,
    const float* __restrict__ A1, const unsigned short* __restrict__ W1,
    const float* __restrict__ b1, float* __restrict__ C1) {
  int bid = blockIdx.x;
  if (bid < 32) gemm_body(A0, W0, b0, C0, bid >> 2, bid & 3);
  else { bid -= 32; gemm_body(A1, W1, b1, C1, bid >> 2, bid & 3); }
}

// ---------------------------------------------------------------------------
// Fused K-projection + scores. One block per (b,m): computes the full
// K[b,m,:,:] tile (128 rows x 512 features), writes it to Kbf (for the edge
// GEMM) AND keeps it in LDS for the scores phase (saves the 134 MB HBM
// re-read of the old scores_kernel).
//   sout[b,h,m,n] = scale * q[b,m,h*32:]·K[b,m,n,h*32:]   (masked on n)
//   sinT[b,h,m,n] = scale * q[b,n,h*32:]·K[b,m,n,h*32:]   (masked on m)
// 512 threads (8 waves: wm = wave>>2, wn = wave&3), 128x512 tile,
// DEPTH-3 staging pipeline with counted vmcnt(6) (6 gll16/lane/step).
// Dynamic LDS = 3*49152 = 147456 B; after the K-loop it is reused as
// K_lds[128][512] bf16 (swizzled, 131072 B) + so_l/si_l[16][128] (16384 B).
__global__ __launch_bounds__(512, 2) void kproj_scores_kernel(
    const float* __restrict__ A, const unsigned short* __restrict__ WT,
    const float* __restrict__ bias, unsigned short* __restrict__ Kbf,
    const float* __restrict__ qw, const int* __restrict__ mask,
    float* __restrict__ sout, float* __restrict__ sinT) {
  constexpr int STAGEB = 16384 + 32768;   // A f32 16KB + B bf16 32KB per stage
  extern __shared__ char smem[];
  const int bm = blockIdx.x;              // b*128 + m
  const int row0 = bm << 7;
  const int b = bm >> 7;
  const int t = threadIdx.x;
  const int wave = t >> 6, lane = t & 63;
  const int wm = wave >> 2, wn = wave & 3;
  const int l15 = lane & 15, q4 = lane >> 4;

  f32x4 acc[4][8];
#pragma unroll
  for (int i = 0; i < 4; ++i)
#pragma unroll
    for (int j = 0; j < 8; ++j)
#pragma unroll
      for (int r = 0; r < 4; ++r) acc[i][j][r] = 0.0f;

  // Stage tile ki into LDS stage s. 6 gll16 per lane (2 A + 4 B).
  auto STAGE = [&](int ki, int s) {
    const int k0 = ki * 32;
    char* sa = smem + s * STAGEB;
    float* Asf = (float*)sa;              // 128x32 f32, XOR-swizzled
#pragma unroll
    for (int c = 0; c < 2; ++c) {
      int ar = (wave * 2 + c) * 8 + (lane >> 3);
      int p = (lane & 7) >> 1, h = lane & 1;
      int gcol = ((p ^ (ar & 3)) << 3) + (h << 2);
      gll16(A + (size_t)(row0 + ar) * 512 + k0 + gcol,
            Asf + (size_t)(wave * 2 + c) * 256);
    }
    unsigned short* Bsb = (unsigned short*)(sa + 16384);  // 512x32 bf16
#pragma unroll
    for (int c = 0; c < 4; ++c) {
      int br = (wave * 4 + c) * 16 + (lane >> 2);
      int gq = (lane & 3) ^ (br & 3);
      gll16(WT + (size_t)br * 512 + k0 + gq * 8,
            Bsb + (size_t)(wave * 4 + c) * 512);
    }
  };

  STAGE(0, 0);
  STAGE(1, 1);

#pragma unroll
  for (int ki = 0; ki < 16; ++ki) {
    if (ki < 15) asm volatile("s_waitcnt vmcnt(6)" ::: "memory");
    else         asm volatile("s_waitcnt vmcnt(0)" ::: "memory");
    __builtin_amdgcn_s_barrier();
    __builtin_amdgcn_sched_barrier(0);
    if (ki + 2 < 16) STAGE(ki + 2, (ki + 2) % 3);

    char* sc = smem + (ki % 3) * STAGEB;
    float* Asf = (float*)sc;
    unsigned short* Bs = (unsigned short*)(sc + 16384);
    bf16x8 bfr[8], af[4];
#pragma unroll
    for (int nt = 0; nt < 8; ++nt) {
      int brow = wn * 128 + nt * 16 + l15;
      bfr[nt] = *(const bf16x8*)&Bs[brow * 32 + ((q4 ^ (brow & 3)) << 3)];
    }
#pragma unroll
    for (int mt = 0; mt < 4; ++mt) {
      int arow = wm * 64 + mt * 16 + l15;
      const float* ap = &Asf[arow * 32 + ((q4 ^ (arow & 3)) << 3)];
      f32x4 v0 = *(const f32x4*)ap;
      f32x4 v1 = *(const f32x4*)(ap + 4);
      union { unsigned d[4]; bf16x8 v; } u;
      u.d[0] = pack2(v0[0], v0[1]); u.d[1] = pack2(v0[2], v0[3]);
      u.d[2] = pack2(v1[0], v1[1]); u.d[3] = pack2(v1[2], v1[3]);
      af[mt] = u.v;
    }
#pragma unroll
    for (int mt = 0; mt < 4; ++mt)
#pragma unroll
      for (int nt = 0; nt < 8; ++nt)
        acc[mt][nt] = __builtin_amdgcn_mfma_f32_16x16x32_bf16(af[mt], bfr[nt], acc[mt][nt], 0, 0, 0);
  }
  __syncthreads();   // staging LDS dead; safe to repurpose below

  // ---- epilogue: write Kbf (global) and K_lds (swizzled bf16)
  unsigned short* K_lds = (unsigned short*)smem;   // [128][512], 16B-chunk XOR swizzle
  float* so_l = (float*)(smem + 131072);           // [16][128], 4-col-block swizzle
  float* si_l = so_l + 16 * 128;
#pragma unroll
  for (int mt = 0; mt < 4; ++mt) {
#pragma unroll
    for (int nt = 0; nt < 8; ++nt) {
      int gcol = wn * 128 + nt * 16 + l15;
      float bv = bias[gcol];
#pragma unroll
      for (int r = 0; r < 4; ++r) {
        int gl = wm * 64 + mt * 16 + q4 * 4 + r;   // local row n
        unsigned short hv = f2bf(acc[mt][nt][r] + bv);
        Kbf[(size_t)(row0 + gl) * 512 + gcol] = hv;
        unsigned byteo = (unsigned)(gl * 1024) +
                         ((2u * (unsigned)gcol) ^ (((unsigned)gl & 7u) << 4));
        *(unsigned short*)((char*)K_lds + byteo) = hv;
      }
    }
  }
  __syncthreads();   // K_lds fully written

  // ---- scores phase (no per-iteration barriers)
  const float scale = 0.17677669529663687f;        // 1/sqrt(32)
  const int maskm = mask[bm];
  float qmr[8];
  {
    const float* qp = qw + (size_t)bm * 512 + lane * 8;
    f32x4 a = *(const f32x4*)qp, bq = *(const f32x4*)(qp + 4);
#pragma unroll
    for (int j = 0; j < 4; ++j) { qmr[j] = a[j]; qmr[4 + j] = bq[j]; }
  }
#pragma unroll
  for (int it = 0; it < 16; ++it) {
    int n = it * 8 + wave;
    unsigned kbyte = (unsigned)(n * 1024) + (((unsigned)lane * 16u) ^ (((unsigned)n & 7u) << 4));
    uint4 kv = *(const uint4*)((const char*)K_lds + kbyte);
    const float* qnp = qw + (size_t)(b * 128 + n) * 512 + lane * 8;
    f32x4 qa = *(const f32x4*)qnp, qb = *(const f32x4*)(qnp + 4);
    float qnr[8];
#pragma unroll
    for (int j = 0; j < 4; ++j) { qnr[j] = qa[j]; qnr[4 + j] = qb[j]; }
    unsigned vals[4] = {kv.x, kv.y, kv.z, kv.w};
    float so = 0.f, si = 0.f;
#pragma unroll
    for (int j = 0; j < 4; ++j) {
      float k0 = bf2f((unsigned short)(vals[j] & 0xFFFFu));
      float k1 = bf2f((unsigned short)(vals[j] >> 16));
      so += qmr[2 * j] * k0 + qmr[2 * j + 1] * k1;
      si += qnr[2 * j] * k0 + qnr[2 * j + 1] * k1;
    }
    so += __shfl_xor(so, 1); so += __shfl_xor(so, 2);
    si += __shfl_xor(si, 1); si += __shfl_xor(si, 2);
    int maskn = mask[b * 128 + n];
    if ((lane & 3) == 0) {
      int h = lane >> 2;
      int idx = h * 128 + (n ^ ((h & 7) << 2));    // 4-col-block swizzle
      so_l[idx] = maskn ? so * scale : -INFINITY;
      si_l[idx] = maskm ? si * scale : -INFINITY;
    }
  }
  __syncthreads();
  {
    int h = t >> 5, c4 = (t & 31) * 4;
    int idx = h * 128 + (c4 ^ ((h & 7) << 2));
    f32x4 vo = *(const f32x4*)&so_l[idx];
    f32x4 vi = *(const f32x4*)&si_l[idx];
    size_t base = ((size_t)(b * 16 + h) * 128 + (size_t)(bm & 127)) * 128 + c4;
    *(f32x4*)&sout[base] = vo;
    *(f32x4*)&sinT[base] = vi;
  }
}

// ---------------------------------------------------------------------------
// Big GEMM (edge output): 128x256 tile, 3-stage pipelined staging with
// counted vmcnt(6). A bf16 (Kbf), scaled per (row, ki=head) by msg -> C f32.
// msg rows preloaded once into Ms[16][128]. grid = 2048; dynamic LDS 81920.
__global__ __launch_bounds__(256, 2) void gemm2e_kernel(
    const unsigned short* __restrict__ Aptr, const unsigned short* __restrict__ WT,
    const float* __restrict__ bias, float* __restrict__ Cptr,
    const float* __restrict__ msg) {
  constexpr int DEPTH  = 3;
  constexpr int ABYTES = 8192;
  constexpr int STAGEB = ABYTES + 16384;
  extern __shared__ char smem[];
  float* Msh = (float*)(smem + DEPTH * STAGEB);

  const int bid = blockIdx.x;
  const int rb = bid >> 1, cb = bid & 1;
  const int row0 = rb * 128, col0 = cb * 256;
  const int t = threadIdx.x;
  const int wave = t >> 6, lane = t & 63;
  const int wm = wave >> 1, wn = wave & 1;
  const int l15 = lane & 15, q4 = lane >> 4;

  f32x4 acc[4][8];
#pragma unroll
  for (int i = 0; i < 4; ++i)
#pragma unroll
    for (int j = 0; j < 8; ++j)
#pragma unroll
      for (int r = 0; r < 4; ++r) acc[i][j][r] = 0.0f;

  auto STAGE = [&](int ki, int s) {
    const int k0 = ki * 32;
    char* sa = smem + s * STAGEB;
    unsigned short* Abf = (unsigned short*)sa;
#pragma unroll
    for (int c = 0; c < 2; ++c) {
      int ar = (wave * 2 + c) * 16 + (lane >> 2);
      int gq = (lane & 3) ^ (ar & 3);
      gll16(Aptr + (size_t)(row0 + ar) * 512 + k0 + gq * 8,
            Abf + (size_t)(wave * 2 + c) * 512);
    }
    unsigned short* Bsb = (unsigned short*)(sa + ABYTES);
#pragma unroll
    for (int c = 0; c < 4; ++c) {
      int br = (wave * 4 + c) * 16 + (lane >> 2);
      int gq = (lane & 3) ^ (br & 3);
      gll16(WT + (size_t)(col0 + br) * 512 + k0 + gq * 8,
            Bsb + (size_t)(wave * 4 + c) * 512);
    }
  };

  {
    int b = row0 >> 14, m = (row0 >> 7) & 127;
    size_t msbase = (size_t)(b * 16) * 16384 + (size_t)m * 128;
    int h = t >> 4, n8 = (t & 15) * 8;
    const float* mp = msg + msbase + (size_t)h * 16384 + n8;
    f32x4 m0 = *(const f32x4*)mp;
    f32x4 m1 = *(const f32x4*)(mp + 4);
    *(f32x4*)&Msh[h * 128 + n8] = m0;
    *(f32x4*)&Msh[h * 128 + n8 + 4] = m1;
    __syncthreads();
  }

  STAGE(0, 0);
  STAGE(1, 1);

#pragma unroll
  for (int ki = 0; ki < 16; ++ki) {
    if (ki < 15) asm volatile("s_waitcnt vmcnt(6)" ::: "memory");
    else         asm volatile("s_waitcnt vmcnt(0)" ::: "memory");
    __builtin_amdgcn_s_barrier();
    __builtin_amdgcn_sched_barrier(0);
    if (ki + 2 < 16) STAGE(ki + 2, (ki + 2) % 3);

    char* sc = smem + (ki % 3) * STAGEB;
    unsigned short* Bs = (unsigned short*)(sc + ABYTES);
    bf16x8 bfr[8], af[4];
#pragma unroll
    for (int nt = 0; nt < 8; ++nt) {
      int brow = wn * 128 + nt * 16 + l15;
      bfr[nt] = *(const bf16x8*)&Bs[brow * 32 + ((q4 ^ (brow & 3)) << 3)];
    }
    unsigned short* Abf = (unsigned short*)sc;
#pragma unroll
    for (int mt = 0; mt < 4; ++mt) {
      int arow = wm * 64 + mt * 16 + l15;
      union { unsigned d[4]; bf16x8 v; } u;
      u.v = *(const bf16x8*)&Abf[arow * 32 + ((q4 ^ (arow & 3)) << 3)];
      float mv = Msh[ki * 128 + arow];
      u.d[0] = scale_pair(u.d[0], mv);
      u.d[1] = scale_pair(u.d[1], mv);
      u.d[2] = scale_pair(u.d[2], mv);
      u.d[3] = scale_pair(u.d[3], mv);
      af[mt] = u.v;
    }
#pragma unroll
    for (int mt = 0; mt < 4; ++mt)
#pragma unroll
      for (int nt = 0; nt < 8; ++nt)
        acc[mt][nt] = __builtin_amdgcn_mfma_f32_16x16x32_bf16(af[mt], bfr[nt], acc[mt][nt], 0, 0, 0);
  }
#pragma unroll
  for (int mt = 0; mt < 4; ++mt) {
#pragma unroll
    for (int nt = 0; nt < 8; ++nt) {
      int gcol = col0 + wn * 128 + nt * 16 + l15;
      float bv = bias[gcol];
#pragma unroll
      for (int r = 0; r < 4; ++r) {
        int grow = row0 + wm * 64 + mt * 16 + q4 * 4 + r;
        Cptr[(size_t)grow * 512 + gcol] = acc[mt][nt][r] + bv;
      }
    }
  }
}

// ---------------------------------------------------------------------------
// Batched 128x128 transpose: dst[mat][y][x] = src[mat][x][y].
__global__ __launch_bounds__(256) void tr128_kernel(const float* __restrict__ src,
                                                    float* __restrict__ dst) {
  __shared__ float T[64][65];
  int bid = blockIdx.x;
  int mat = bid >> 2, tile = bid & 3;
  int ti = tile >> 1, tj = tile & 1;
  const float* s = src + (size_t)mat * 16384;
  float* d = dst + (size_t)mat * 16384;
  int t = threadIdx.x;
  int r = t >> 2, cq = (t & 3) * 16;
#pragma unroll
  for (int j = 0; j < 16; ++j) T[r][cq + j] = s[(size_t)(ti * 64 + r) * 128 + tj * 64 + cq + j];
  __syncthreads();
  int c = t >> 2, rq = (t & 3) * 16;
#pragma unroll
  for (int j = 0; j < 16; ++j) d[(size_t)(tj * 64 + c) * 128 + ti * 64 + rq + j] = T[rq + j][c];
}

// ---------------------------------------------------------------------------
// Fused: out_attn = softmax(sout row), in_attn = softmax(msgb row),
// message = ((r==c)? in : out+in) * adjsm -> msgb, all row-local.
// grid = B*H*N/4 = 4096 blocks x 256 threads (4 rows/block).
__global__ __launch_bounds__(256) void smmsg_kernel(const float* __restrict__ sout,
                                                    float* __restrict__ msgb,
                                                    const float* __restrict__ adjsm) {
  int row = blockIdx.x * 4 + (threadIdx.x >> 6);   // (b*16+h)*128 + i
  int lane = threadIdx.x & 63;
  int bh = row >> 7, b = bh >> 4, i = row & 127;
  const float* op = sout + (size_t)row * 128;
  float* ip = msgb + (size_t)row * 128;
  float o0 = op[lane], o1 = op[lane + 64];
  float i0 = ip[lane], i1 = ip[lane + 64];
  float mo = fmaxf(o0, o1), mi = fmaxf(i0, i1);
#pragma unroll
  for (int o = 32; o; o >>= 1) {
    mo = fmaxf(mo, __shfl_xor(mo, o));
    mi = fmaxf(mi, __shfl_xor(mi, o));
  }
  float eo0 = __expf(o0 - mo), eo1 = __expf(o1 - mo);
  float ei0 = __expf(i0 - mi), ei1 = __expf(i1 - mi);
  float so = eo0 + eo1, si = ei0 + ei1;
#pragma unroll
  for (int o = 32; o; o >>= 1) {
    so += __shfl_xor(so, o);
    si += __shfl_xor(si, o);
  }
  float invo = 1.0f / so, invi = 1.0f / si;
  float ao0 = eo0 * invo, ao1 = eo1 * invo;
  float ai0 = ei0 * invi, ai1 = ei1 * invi;
  float m0 = (lane == i) ? ai0 : (ao0 + ai0);
  float m1 = (lane + 64 == i) ? ai1 : (ao1 + ai1);
  const float* ar = adjsm + ((size_t)b * 128 + i) * 128;
  ip[lane] = m0 * ar[lane];
  ip[lane + 64] = m1 * ar[lane + 64];
}

// ---------------------------------------------------------------------------
// node_hidden: xpre[b, i, h*32+d] = sum_j msg[b,h,i,j] * v[b,j,h*32+d]
__global__ __launch_bounds__(256) void node_kernel(const float* __restrict__ msg,
                                                   const float* __restrict__ vw,
                                                   float* __restrict__ xpre) {
  __shared__ float V[128 * 36];
  __shared__ float Mg[64 * 132];
  int bid = blockIdx.x;
  int bh = bid >> 1, half = bid & 1;
  int b = bh >> 4, h = bh & 15;
  int t = threadIdx.x;
#pragma unroll
  for (int i = 0; i < 16; ++i) {
    int idx = t + i * 256;
    int j = idx >> 5, dk = idx & 31;
    V[j * 36 + dk] = vw[((size_t)b * 128 + j) * 512 + h * 32 + dk];
  }
  const float* mrow = msg + (size_t)bh * 16384 + (size_t)half * 64 * 128;
#pragma unroll
  for (int i = 0; i < 32; ++i) {
    int idx = t + i * 256;
    int r = idx >> 7, c = idx & 127;
    Mg[r * 132 + c] = mrow[idx];
  }
  __syncthreads();
  int il = t >> 2, d0 = (t & 3) * 8;
  float acc[8] = {0, 0, 0, 0, 0, 0, 0, 0};
  for (int j = 0; j < 128; ++j) {
    float mv = Mg[il * 132 + j];
#pragma unroll
    for (int d = 0; d < 8; ++d) acc[d] += mv * V[j * 36 + d0 + d];
  }
  float* xp = xpre + ((size_t)b * 128 + half * 64 + il) * 512 + h * 32 + d0;
#pragma unroll
  for (int d = 0; d < 8; ++d) xp[d] = acc[d];
}

// ---------------------------------------------------------------------------
extern "C" void kernel_launch(void* const* d_in, const int* in_sizes, int n_in,
                              void* d_out, int out_size, void* d_ws, size_t ws_size,
                              hipStream_t stream) {
  const float* q_node   = (const float*)d_in[0];
  const float* v_node   = (const float*)d_in[1];
  const float* key_edge = (const float*)d_in[2];
  const float* adjm     = (const float*)d_in[3];
  const int*   mask     = (const int*)d_in[4];
  const float* Wq = (const float*)d_in[5];
  const float* bq = (const float*)d_in[6];
  const float* Wk = (const float*)d_in[7];
  const float* bk = (const float*)d_in[8];
  const float* Wv = (const float*)d_in[9];
  const float* bv = (const float*)d_in[10];
  const float* Wo = (const float*)d_in[11];
  const float* bo = (const float*)d_in[12];
  const float* We = (const float*)d_in[13];
  const float* be = (const float*)d_in[14];
  const float* lam = (const float*)d_in[15];

  char* ws = (char*)d_ws;
  unsigned short* Kbf   = (unsigned short*)(ws);                 // 134,217,728 B
  float* sout  = (float*)(ws + 134217728);                       //   8,388,608 B
  float* sinT  = (float*)(ws + 142606336);                       //   8,388,608 B
  float* msgb  = (float*)(ws + 150994944);                       //   8,388,608 B
  float* adjsm = (float*)(ws + 159383552);                       //     524,288 B
  float* qw    = (float*)(ws + 159907840);                       //   2,097,152 B
  float* vw    = (float*)(ws + 162004992);                       //   2,097,152 B
  float* xpre  = (float*)(ws + 164102144);                       //   2,097,152 B
  unsigned short* WqT = (unsigned short*)(ws + 166199296);       //   524,288 B each
  unsigned short* WkT = WqT + 262144;
  unsigned short* WvT = WkT + 262144;
  unsigned short* WoT = WvT + 262144;
  unsigned short* WeT = WoT + 262144;
  // total ws usage: 168,820,736 bytes (unchanged)

  float* out_x = (float*)d_out;          // (B,N,D)   = 524288 f32
  float* out_e = out_x + 524288;         // (B,N,N,D) = 67108864 f32

  wt5_kernel<<<320, 256, 0, stream>>>(Wq, Wk, Wv, Wo, We, WqT, WkT, WvT, WoT, WeT);
  adj_kernel<<<256, 256, 0, stream>>>(adjm, mask, lam, adjsm);

  gemm_qv_kernel<<<64, 256, 0, stream>>>(q_node, WqT, bq, qw, v_node, WvT, bv, vw);

  kproj_scores_kernel<<<1024, 512, 147456, stream>>>(key_edge, WkT, bk, Kbf,
                                                     qw, mask, sout, sinT);

  tr128_kernel<<<512, 256, 0, stream>>>(sinT, msgb);
  smmsg_kernel<<<4096, 256, 0, stream>>>(sout, msgb, adjsm);
  node_kernel<<<256, 256, 0, stream>>>(msgb, vw, xpre);

  gemm_kernel<<<32, 256, 0, stream>>>(xpre, WoT, bo, out_x);
  gemm2e_kernel<<<2048, 256, 81920, stream>>>(Kbf, WeT, be, out_e, msgb);
}